// Round 3
// baseline (402.794 us; speedup 1.0000x reference)
//
#include <hip/hip_runtime.h>

// OccupancyConnectivity on a 385^3 fp32 grid (z innermost, y stride 385,
// x stride 148225). total = sum over 3 forward axes of |a[p+off]-a[p]|.
//
// Plane-marching tiles: each block owns a 64(z) x 16(y) tile and marches
// 25 consecutive x-planes. Per plane: stage tile + halo (row y0+16, col
// z0+64) into double-buffered LDS; z-diffs and y-diffs computed from LDS,
// x-diffs from previous plane's registers. Every element is fetched ~once
// (halo ~+8%); no long-distance concurrent streams. 8 fixup blocks handle
// the three boundary lines (y=384 z-diffs, z=384 y-diffs, x-diffs on both).

constexpr int G     = 385;
constexpr int PLANE = G * G;             // 148225
constexpr int ZT = 6, YT = 24, XC = 16;  // tile grid: 6 z-tiles(64) x 24 y-tiles(16) x 16 x-chunks
constexpr int XP = 384 / XC;             // 24 x-pairs per chunk (25 planes touched)

#define TPB   256
#define FIXB  8
#define TILES (ZT * YT * XC)             // 2304
#define ALLB  (TILES + FIXB)             // 2312

typedef float f4v __attribute__((ext_vector_type(4)));
typedef f4v f4u __attribute__((aligned(4)));
static __device__ __forceinline__ f4v ld4(const float* p) { return *(const f4u*)p; }

__global__ __launch_bounds__(TPB) void occ_conn_main(
    const float* __restrict__ a, float* __restrict__ ws)
{
    float s = 0.f;
    const int bid = blockIdx.x;

    __shared__ float T[2][17][68];  // double buffer; row stride 68 (272 B, 16B-aligned)

    if (bid < FIXB) {
        // ---- boundary-line fixups (adds only; ~3 MB of reads) ----
        const unsigned ft = (unsigned)bid * TPB + threadIdx.x;
        const unsigned NF = FIXB * TPB;

        // F1: z-diffs on the y=384 row: x in [0,385), z in [0,384)
        for (unsigned j = ft; j < 385u * 384u; j += NF) {
            const unsigned x = j / 384u, z = j - x * 384u;
            const unsigned p = x * (unsigned)PLANE + 384u * (unsigned)G + z;
            s += fabsf(a[p + 1] - a[p]);
        }
        // F2: y-diffs on the z=384 column: x in [0,385), y in [0,384)
        for (unsigned j = ft; j < 385u * 384u; j += NF) {
            const unsigned x = j / 384u, y = j - x * 384u;
            const unsigned p = x * (unsigned)PLANE + y * (unsigned)G + 384u;
            s += fabsf(a[p + G] - a[p]);
        }
        // F3a: x-diffs on y=384: x in [0,384), z in [0,385)
        for (unsigned j = ft; j < 384u * 385u; j += NF) {
            const unsigned x = j / 385u, z = j - x * 385u;
            const unsigned p = x * (unsigned)PLANE + 384u * (unsigned)G + z;
            s += fabsf(a[p + PLANE] - a[p]);
        }
        // F3b: x-diffs on z=384: x in [0,384), y in [0,384)
        for (unsigned j = ft; j < 384u * 384u; j += NF) {
            const unsigned x = j / 384u, y = j - x * 384u;
            const unsigned p = x * (unsigned)PLANE + y * (unsigned)G + 384u;
            s += fabsf(a[p + PLANE] - a[p]);
        }
    } else {
        // ---- plane-marching tile ----
        int t = bid - FIXB;
        const int bc = t & (XC - 1); t >>= 4;      // x-chunk
        const int by = t % YT;
        const int bz = t / YT;
        const int tz = threadIdx.x & 15;           // z-group (4 floats)
        const int ty = threadIdx.x >> 4;           // row within tile
        const int P0 = bc * XP, P1 = P0 + XP;      // planes [P0, P1] touched
        const bool last = (bc == XC - 1);

        const float* pm  = a + (size_t)P0 * PLANE + (size_t)(by * 16 + ty) * G + (bz * 64 + tz * 4);
        const float* ph  = a + (size_t)P0 * PLANE + (size_t)(by * 16 + 16) * G + (bz * 64 + tz * 4);
        const float* pc  = a + (size_t)P0 * PLANE + (size_t)(by * 16 + tz) * G + (bz * 64 + 64);
        const float* pc2 = a + (size_t)P0 * PLANE + (size_t)(by * 16 + 16) * G + (bz * 64 + 64);

        f4v prev;
        for (int x = P0; x <= P1; ++x) {
            const int par = x & 1;
            const f4v cur = ld4(pm);
            *(f4v*)&T[par][ty][tz * 4] = cur;
            if (ty == 0)             *(f4v*)&T[par][16][tz * 4] = ld4(ph);
            if (ty == 1)             T[par][tz][64] = *pc;
            if (ty == 2 && tz == 0)  T[par][16][64] = *pc2;
            __syncthreads();

            // z/y diffs for every plane in [P0,P1); last chunk also does x=384.
            if (x < P1 || last) {
                const float v0 = T[par][ty][tz * 4 + 0];
                const float v1 = T[par][ty][tz * 4 + 1];
                const float v2 = T[par][ty][tz * 4 + 2];
                const float v3 = T[par][ty][tz * 4 + 3];
                const float v4 = T[par][ty][tz * 4 + 4];   // z-halo (tz==15 -> col 64)
                const float u0 = T[par][ty + 1][tz * 4 + 0];
                const float u1 = T[par][ty + 1][tz * 4 + 1];
                const float u2 = T[par][ty + 1][tz * 4 + 2];
                const float u3 = T[par][ty + 1][tz * 4 + 3];
                s += fabsf(v1 - v0) + fabsf(v2 - v1) + fabsf(v3 - v2) + fabsf(v4 - v3);
                s += fabsf(u0 - v0) + fabsf(u1 - v1) + fabsf(u2 - v2) + fabsf(u3 - v3);
            }
            // x-diffs vs previous plane (registers)
            if (x > P0) {
                s += fabsf(cur.x - prev.x) + fabsf(cur.y - prev.y)
                   + fabsf(cur.z - prev.z) + fabsf(cur.w - prev.w);
            }
            prev = cur;
            pm += PLANE; ph += PLANE; pc += PLANE; pc2 += PLANE;
        }
    }

    // wave (64-lane) shuffle reduction
    #pragma unroll
    for (int off = 32; off > 0; off >>= 1) s += __shfl_down(s, off, 64);

    __shared__ float ls[TPB / 64];
    const int lane = threadIdx.x & 63;
    const int wid  = threadIdx.x >> 6;
    if (lane == 0) ls[wid] = s;
    __syncthreads();
    if (threadIdx.x == 0) {
        float tsum = 0.f;
        #pragma unroll
        for (int w = 0; w < TPB / 64; ++w) tsum += ls[w];
        ws[blockIdx.x] = tsum;
    }
}

__global__ __launch_bounds__(256) void occ_conn_final(
    const float* __restrict__ ws, float* __restrict__ out)
{
    float s = 0.f;
    for (int i = threadIdx.x; i < ALLB; i += 256) s += ws[i];
    #pragma unroll
    for (int off = 32; off > 0; off >>= 1) s += __shfl_down(s, off, 64);
    __shared__ float ls[4];
    const int lane = threadIdx.x & 63;
    const int wid  = threadIdx.x >> 6;
    if (lane == 0) ls[wid] = s;
    __syncthreads();
    if (threadIdx.x == 0) out[0] = ls[0] + ls[1] + ls[2] + ls[3];
}

extern "C" void kernel_launch(void* const* d_in, const int* in_sizes, int n_in,
                              void* d_out, int out_size, void* d_ws, size_t ws_size,
                              hipStream_t stream)
{
    const float* a   = (const float*)d_in[0];
    float*       out = (float*)d_out;
    float*       ws  = (float*)d_ws;   // ALLB floats; fully overwritten each call

    occ_conn_main<<<ALLB, TPB, 0, stream>>>(a, ws);
    occ_conn_final<<<1, 256, 0, stream>>>(ws, out);
}

// Round 4
// 316.791 us; speedup vs baseline: 1.2715x; 1.2715x over previous
//
#include <hip/hip_runtime.h>

// OccupancyConnectivity on a 385^3 fp32 grid (z innermost, y stride 385,
// x stride 148225). total = sum over 3 forward axes of |a[p+off]-a[p]|.
//
// Plane-marching 32(y) x 128(z) tiles, 7 planes per block (XC=64 x-chunks).
// Per round: issue ALIGNED b128 global loads for plane x (each row's
// 132-float aligned window, phase phi = W mod 4 recorded implicitly),
// compute plane x-1 diffs from double-buffered LDS (z,y from same buffer;
// x-diff vs the OTHER buffer = plane x-2), barrier, write regs->LDS,
// barrier. All global boundary terms (y=384 row, z=384 column, corner)
// are folded into the edge tiles via the loaded halos. HBM-bound design:
// ~17.4 KB/block-round, 4 blocks/CU resident => ~70 KB in flight per CU.

constexpr int G     = 385;
constexpr int PLANE = G * G;             // 148225

#define TPB  256
#define ZT   3                            // z-tiles of 128 (z in [0,384))
#define YT   12                           // y-tiles of 32 (y in [0,384))
#define XC   64                           // x-chunks of 6 pairs (7 planes)
#define NBLK (ZT * YT * XC)               // 2304 blocks
#define S    148                          // LDS row stride in floats

typedef float f4v __attribute__((ext_vector_type(4)));
static __device__ __forceinline__ f4v ld4(const float* p) { return *(const f4v*)p; }

__global__ __launch_bounds__(TPB) void occ_conn_main(
    const float* __restrict__ a, float* __restrict__ ws)
{
    __shared__ float T[2][33][S];          // 2 x 33 rows x 148 floats = 39072 B
    float s = 0.f;

    const int tz = threadIdx.x & 31;       // z-chunk / column lane
    const int ty = threadIdx.x >> 5;       // row group 0..7

    int t = blockIdx.x;
    const int bc = t % XC;  t /= XC;
    const int by = t % YT;  t /= YT;
    const int bz = t;                      // 0..2
    const unsigned gy0 = by * 32u;
    const unsigned gz0 = bz * 128u;
    const int  P0    = bc * 6;
    const bool lastc = (bc == XC - 1);
    const bool ey    = (by == YT - 1);     // halo row 32 is global y=384
    const bool ez    = (bz == ZT - 1);     // halo col zl=128 is global z=384

    f4v m0, m1, m2, m3, h;

    for (int tt = 0; tt <= 7; ++tt) {
        const int x = P0 + tt;

        // ---- [1] issue aligned global loads for plane x (tt<=6) ----
        if (tt <= 6) {
            const unsigned base = (unsigned)x * (unsigned)PLANE + gy0 * (unsigned)G + gz0;
            const unsigned W0 = base + (unsigned)ty * (unsigned)G;
            const unsigned W1 = W0 +  8u * (unsigned)G;
            const unsigned W2 = W0 + 16u * (unsigned)G;
            const unsigned W3 = W0 + 24u * (unsigned)G;
            m0 = ld4(a + (W0 - (W0 & 3u)) + 4u * (unsigned)tz);
            m1 = ld4(a + (W1 - (W1 & 3u)) + 4u * (unsigned)tz);
            m2 = ld4(a + (W2 - (W2 & 3u)) + 4u * (unsigned)tz);
            m3 = ld4(a + (W3 - (W3 & 3u)) + 4u * (unsigned)tz);
            if (ty == 0) {                         // halo row 32, chunks 0..31
                const unsigned W32 = base + 32u * (unsigned)G;
                h = ld4(a + (W32 - (W32 & 3u)) + 4u * (unsigned)tz);
            } else if (ty == 1) {                  // chunk 32 of row tz
                const unsigned Wr = base + (unsigned)tz * (unsigned)G;
                h = ld4(a + (Wr - (Wr & 3u)) + 128u);
            } else if (ty == 2 && tz == 0) {       // chunk 32 of halo row
                const unsigned W32 = base + 32u * (unsigned)G;
                h = ld4(a + (W32 - (W32 & 3u)) + 128u);
            }
        }

        // ---- [2] compute on plane xc = x-1 from LDS (tt>=1) ----
        if (tt >= 1) {
            const int xc = x - 1;
            const float (*C)[S]  = T[(tt - 1) & 1];   // plane xc
            const float (*Pv)[S] = T[tt & 1];         // plane xc-1 (valid when tt>=2)
            const bool zy = (tt <= 6) || (lastc && tt == 7);
            const bool xd = (tt >= 2);

            #pragma unroll
            for (int rr = 0; rr < 4; ++rr) {
                const int r = ty + 8 * rr;
                const unsigned phi  = (unsigned)(xc + (int)gy0 + r) & 3u;  // = W mod 4
                const unsigned phin = (phi + 1u) & 3u;                     // row r+1 phase
                const unsigned phip = (phi + 3u) & 3u;                     // plane xc-1 phase
                #pragma unroll
                for (int j = 0; j < 4; ++j) {
                    const int zl = tz + 32 * j;
                    const float v = C[r][phi + zl];
                    if (zy) {
                        s += fabsf(C[r][phi + zl + 1] - v);      // z-diff
                        s += fabsf(C[r + 1][phin + zl] - v);     // y-diff
                    }
                    if (xd) s += fabsf(v - Pv[r][phip + zl]);    // x-diff
                }
            }

            // ---- boundary extras (folded fixups) ----
            if (ez && ty == 4) {
                // z=384 column: y-diff + x-diff for rows 0..31 (thread tz -> row tz)
                const int r = tz;
                const unsigned phi  = (unsigned)(xc + (int)gy0 + r) & 3u;
                const unsigned phin = (phi + 1u) & 3u;
                const unsigned phip = (phi + 3u) & 3u;
                const float v = C[r][phi + 128];
                if (zy) s += fabsf(C[r + 1][phin + 128] - v);
                if (xd) s += fabsf(v - Pv[r][phip + 128]);
            }
            if (ey && ty == 5) {
                // y=384 halo row: z-diffs + x-diffs over zl in [0,128)
                const unsigned phi  = (unsigned)(xc + (int)gy0 + 32) & 3u;
                const unsigned phip = (phi + 3u) & 3u;
                #pragma unroll
                for (int j = 0; j < 4; ++j) {
                    const int zl = tz + 32 * j;
                    const float v = C[32][phi + zl];
                    if (zy) s += fabsf(C[32][phi + zl + 1] - v);
                    if (xd) s += fabsf(v - Pv[32][phip + zl]);
                }
            }
            if (ey && ez && ty == 6 && tz == 0 && xd) {
                // corner (y=384, z=384): x-diff only
                const unsigned phi  = (unsigned)(xc + (int)gy0 + 32) & 3u;
                const unsigned phip = (phi + 3u) & 3u;
                s += fabsf(C[32][phi + 128] - Pv[32][phip + 128]);
            }
        }

        __syncthreads();   // all reads of buf[tt&1] done before overwrite

        // ---- [3] write this round's loads into buf[tt&1] (tt<=6) ----
        if (tt <= 6) {
            float (*B)[S] = T[tt & 1];
            *(f4v*)&B[ty +  0][4 * tz] = m0;
            *(f4v*)&B[ty +  8][4 * tz] = m1;
            *(f4v*)&B[ty + 16][4 * tz] = m2;
            *(f4v*)&B[ty + 24][4 * tz] = m3;
            if      (ty == 0)            *(f4v*)&B[32][4 * tz] = h;
            else if (ty == 1)            *(f4v*)&B[tz][128]    = h;
            else if (ty == 2 && tz == 0) *(f4v*)&B[32][128]    = h;
        }
        __syncthreads();
    }

    // ---- block reduction ----
    #pragma unroll
    for (int off = 32; off > 0; off >>= 1) s += __shfl_down(s, off, 64);
    __shared__ float ls[TPB / 64];
    const int lane = threadIdx.x & 63;
    const int wid  = threadIdx.x >> 6;
    if (lane == 0) ls[wid] = s;
    __syncthreads();
    if (threadIdx.x == 0) {
        float tsum = 0.f;
        #pragma unroll
        for (int w = 0; w < TPB / 64; ++w) tsum += ls[w];
        ws[blockIdx.x] = tsum;
    }
}

__global__ __launch_bounds__(256) void occ_conn_final(
    const float* __restrict__ ws, float* __restrict__ out)
{
    float s = 0.f;
    for (int i = threadIdx.x; i < NBLK; i += 256) s += ws[i];
    #pragma unroll
    for (int off = 32; off > 0; off >>= 1) s += __shfl_down(s, off, 64);
    __shared__ float ls[4];
    const int lane = threadIdx.x & 63;
    const int wid  = threadIdx.x >> 6;
    if (lane == 0) ls[wid] = s;
    __syncthreads();
    if (threadIdx.x == 0) out[0] = ls[0] + ls[1] + ls[2] + ls[3];
}

extern "C" void kernel_launch(void* const* d_in, const int* in_sizes, int n_in,
                              void* d_out, int out_size, void* d_ws, size_t ws_size,
                              hipStream_t stream)
{
    const float* a   = (const float*)d_in[0];
    float*       out = (float*)d_out;
    float*       ws  = (float*)d_ws;   // NBLK floats; fully overwritten each call

    occ_conn_main<<<NBLK, TPB, 0, stream>>>(a, ws);
    occ_conn_final<<<1, 256, 0, stream>>>(ws, out);
}